// Round 1
// baseline (377.532 us; speedup 1.0000x reference)
//
#include <hip/hip_runtime.h>
#include <stdint.h>

typedef _Float16 f16;
typedef _Float16 f16x2 __attribute__((ext_vector_type(2)));
typedef _Float16 f16x8 __attribute__((ext_vector_type(8)));
typedef float f32x4 __attribute__((ext_vector_type(4)));

#define NB 16
#define NH 256
#define NW 256
#define NC 32
#define NK 5

// ---------------- multi-block pipelined version ----------------
// 16 chunks of 16 cols per batch; each block computes 48 cols (own + 16-col
// halo each side). Every 8 rows blocks exchange their own 16 cols of x via
// global mailboxes (light-cone: halo 16 = 2 cols/row * 8 rows, exactly tight).
#define CW 16
#define GC 16              // chunks per batch
#define XSTR 40            // f16 row stride (permuted channel pairs + pad)
#define XROWS 52           // 48 compute cols + 2 zero-pad rows each side

#define FLAG_STRIDE 16     // u32 stride between flags (64B padding)
#define MAIL_BASE 4096     // u32 offset of mailbox region in ws (16KB flags)
#define MAIL_WORDS 256     // u32 per slot: 16 cols * 16 channel-pairs

__device__ __forceinline__ void lds_barrier() {
  asm volatile("s_waitcnt lgkmcnt(0)\n\ts_barrier" ::: "memory");
}

__global__ __launch_bounds__(192, 1)
void mvcnn_down_mb(const float* __restrict__ in, const float* __restrict__ wt,
                   const float* __restrict__ bias, float* __restrict__ out,
                   uint32_t* __restrict__ ws) {
  __shared__ __align__(16) f16 xpad[2][XROWS * XSTR];

  const int bid  = blockIdx.x;
  const int b    = bid & 15;     // batch  (bid%8 => XCD: chunks of a batch co-XCD)
  const int ck   = bid >> 4;     // chunk
  const int t    = threadIdx.x;
  const int lane = t & 63;
  const int wv   = t >> 6;       // 0: left-halo tile, 1: own tile, 2: right-halo
  const int n16  = lane & 15;
  const int q    = lane >> 4;

  // halo tiles beyond the image edge are inactive (stay zero == image padding)
  const bool act = (wv == 1) || (wv == 0 ? (ck > 0) : (ck < GC - 1));

  // ---- resident weight B-fragments, k-permuted to match xpad layout ----
  f16x8 bfrag[NK][2];
  #pragma unroll
  for (int tap = 0; tap < NK; ++tap) {
    #pragma unroll
    for (int nt = 0; nt < 2; ++nt) {
      f16x8 f;
      #pragma unroll
      for (int j = 0; j < 8; ++j) {
        int cch = q * 4 + (j >> 1) + (j & 1) * 16;
        f[j] = (f16)wt[(cch * NK + tap) * NC + nt * 16 + n16];
      }
      bfrag[tap][nt] = f;
    }
  }
  const float bias0 = bias[n16];
  const float bias1 = bias[16 + n16];

  for (int i = t; i < 2 * XROWS * XSTR; i += 192) (&xpad[0][0])[i] = (f16)0.f;
  __syncthreads();

  const float* inb  = in  + (size_t)b * NH * NW * NC;
  float*       outb = out + (size_t)b * NH * NW * NC;

  const int wo0   = wv * 16 + q * 4;       // local col of r=0 (xpad row wo0+2)
  const int gcol0 = ck * CW - 16 + wo0;    // global col of r=0
  const int arow  = wv * 16 + n16;         // A-operand xpad row base

  uint32_t* flags = ws;                    // flags[bid*FLAG_STRIDE], monotone sync idx
  uint32_t* mail  = ws + MAIL_BASE;        // mail[(bid*2+slot)*MAIL_WORDS + idx]
  const int midx  = (q * 4) * 16 + n16;    // + r*16

  float pf0[8], pf1[8];
  auto load_in_row = [&](int h1, float (&pf)[8]) {
    if (!act) return;
    const float* rp = inb + (size_t)h1 * NW * NC;
    #pragma unroll
    for (int r = 0; r < 4; ++r) {
      int g = gcol0 + r;
      pf[2 * r]     = rp[g * NC + n16];
      pf[2 * r + 1] = rp[g * NC + 16 + n16];
    }
  };

  // ---- stage row 0: x_0 = in_0 everywhere in the compute window ----
  if (act) {
    #pragma unroll
    for (int r = 0; r < 4; ++r) {
      int g = gcol0 + r;
      f16x2 v;
      v[0] = (f16)inb[g * NC + n16];
      v[1] = (f16)inb[g * NC + 16 + n16];
      *(f16x2*)(&xpad[0][(wo0 + r + 2) * XSTR + 2 * n16]) = v;
    }
  }
  load_in_row(1, pf0);
  load_in_row(2, pf1);
  __syncthreads();

  auto body = [&](const int h, float (&pf)[8], f16* xp_cur, f16* xp_nxt) {
    // ---- halo receive (sync rows: h = 8,16,...,248; xp_cur is always xpad[0]) ----
    if (h > 0 && (h & 7) == 0) {
      const uint32_t s  = (uint32_t)(h >> 3);
      const int slot    = (int)(s & 1);
      if ((wv == 0 && ck > 0) || (wv == 2 && ck < GC - 1)) {
        const int nb = (wv == 0) ? (bid - GC) : (bid + GC);
        if (lane == 0) {
          while (__hip_atomic_load(&flags[nb * FLAG_STRIDE],
                                   __ATOMIC_RELAXED, __HIP_MEMORY_SCOPE_AGENT) < s)
            __builtin_amdgcn_s_sleep(2);
        }
        asm volatile("" ::: "memory");  // no hoisting data loads above the spin
        const uint32_t* mb = mail + ((size_t)nb * 2 + slot) * MAIL_WORDS;
        #pragma unroll
        for (int r = 0; r < 4; ++r) {
          uint32_t u = __hip_atomic_load(&mb[midx + r * 16],
                                         __ATOMIC_RELAXED, __HIP_MEMORY_SCOPE_AGENT);
          *(uint32_t*)(&xp_cur[(wo0 + r + 2) * XSTR + 2 * n16]) = u;
        }
      }
      lds_barrier();  // uniform: all waves reach this (h is block-uniform)
    }

    // ---- MFMA: y[w][o] = sum_{tap,k} x[w+tap-2][k] * W[k][tap][o] ----
    f32x4 acc0 = {0.f, 0.f, 0.f, 0.f};
    f32x4 acc1 = {0.f, 0.f, 0.f, 0.f};
    #pragma unroll
    for (int tap = 0; tap < NK; ++tap) {
      f16x8 af = *(const f16x8*)(xp_cur + (arow + tap) * XSTR + q * 8);
      acc0 = __builtin_amdgcn_mfma_f32_16x16x32_f16(af, bfrag[tap][0], acc0, 0, 0, 0);
      acc1 = __builtin_amdgcn_mfma_f32_16x16x32_f16(af, bfrag[tap][1], acc1, 0, 0, 0);
    }

    // ---- epilogue: r = relu(y+b); own tile stores out; stage x_{h+1} ----
    float* orow = outb + (size_t)h * NW * NC;
    uint32_t sb[4] = {0, 0, 0, 0};
    #pragma unroll
    for (int r = 0; r < 4; ++r) {
      float y0 = acc0[r] + bias0; y0 = y0 > 0.f ? y0 : 0.f;
      float y1 = acc1[r] + bias1; y1 = y1 > 0.f ? y1 : 0.f;
      if (wv == 1) {
        int g = gcol0 + r;
        orow[g * NC + n16]      = y0;
        orow[g * NC + 16 + n16] = y1;
      }
      if (h < NH - 1 && act) {
        f16x2 v;
        v[0] = (f16)(pf[2 * r]     + y0);
        v[1] = (f16)(pf[2 * r + 1] + y1);
        *(f16x2*)(&xp_nxt[(wo0 + r + 2) * XSTR + 2 * n16]) = v;
        sb[r] = __builtin_bit_cast(uint32_t, v);
      }
    }

    // ---- halo send (h = 7,15,...,247): publish own 16 cols of x_{h+1} ----
    if (((h + 1) & 7) == 0 && (h + 1) < NH && wv == 1) {
      const uint32_t s = (uint32_t)((h + 1) >> 3);
      const int slot   = (int)(s & 1);
      uint32_t* mb = mail + ((size_t)bid * 2 + slot) * MAIL_WORDS;
      #pragma unroll
      for (int r = 0; r < 4; ++r)
        __hip_atomic_store(&mb[midx + r * 16], sb[r],
                           __ATOMIC_RELAXED, __HIP_MEMORY_SCOPE_AGENT);
      asm volatile("s_waitcnt vmcnt(0)" ::: "memory");  // data at coherent point
      if (lane == 0)
        __hip_atomic_store(&flags[bid * FLAG_STRIDE], s,
                           __ATOMIC_RELAXED, __HIP_MEMORY_SCOPE_AGENT);
    }

    if (h + 3 < NH) load_in_row(h + 3, pf);
    lds_barrier();
  };

  f16* xA = &xpad[0][0];
  f16* xB = &xpad[1][0];
  for (int h = 0; h < NH; h += 2) {
    body(h,     pf0, xA, xB);
    body(h + 1, pf1, xB, xA);
  }
}

__global__ void reset_flags(uint32_t* ws) {
  ws[blockIdx.x * 256 + threadIdx.x] = 0;  // zero the 16KB flag region
}

// ---------------- fallback: proven monolithic kernel (610 µs) ----------------
__global__ __launch_bounds__(1024, 4)
void mvcnn_down(const float* __restrict__ in, const float* __restrict__ wt,
                const float* __restrict__ bias, float* __restrict__ out) {
  __shared__ __align__(16) f16 xpad[2][260 * XSTR];

  const int b    = blockIdx.x;
  const int t    = threadIdx.x;
  const int lane = t & 63;
  const int wv   = t >> 6;
  const int n16  = lane & 15;
  const int q    = lane >> 4;

  f16x8 bfrag[NK][2];
  #pragma unroll
  for (int tap = 0; tap < NK; ++tap) {
    #pragma unroll
    for (int nt = 0; nt < 2; ++nt) {
      f16x8 f;
      #pragma unroll
      for (int j = 0; j < 8; ++j) {
        int cch = q * 4 + (j >> 1) + (j & 1) * 16;
        f[j] = (f16)wt[(cch * NK + tap) * NC + nt * 16 + n16];
      }
      bfrag[tap][nt] = f;
    }
  }
  const float bias0 = bias[n16];
  const float bias1 = bias[16 + n16];

  for (int i = t; i < 2 * 260 * XSTR; i += 1024) (&xpad[0][0])[i] = (f16)0.f;
  __syncthreads();

  const float* inb  = in  + (size_t)b * NH * NW * NC;
  float*       outb = out + (size_t)b * NH * NW * NC;

  const int wo0  = wv * 16 + q * 4;
  const int arow = wv * 16 + n16;

  float pf0[8], pf1[8];
  auto load_in_row = [&](int h1, float (&pf)[8]) {
    const float* rp = inb + (size_t)h1 * NW * NC;
    #pragma unroll
    for (int r = 0; r < 4; ++r) {
      int wo = wo0 + r;
      pf[2 * r]     = rp[wo * NC + n16];
      pf[2 * r + 1] = rp[wo * NC + 16 + n16];
    }
  };

  #pragma unroll
  for (int r = 0; r < 4; ++r) {
    int wo = wo0 + r;
    f16x2 v;
    v[0] = (f16)inb[wo * NC + n16];
    v[1] = (f16)inb[wo * NC + 16 + n16];
    *(f16x2*)(&xpad[0][(wo + 2) * XSTR + 2 * n16]) = v;
  }
  load_in_row(1, pf0);
  load_in_row(2, pf1);
  __syncthreads();

  auto body = [&](const int h, float (&pf)[8], const f16* xp_cur, f16* xp_nxt) {
    f32x4 acc0 = {0.f, 0.f, 0.f, 0.f};
    f32x4 acc1 = {0.f, 0.f, 0.f, 0.f};
    #pragma unroll
    for (int tap = 0; tap < NK; ++tap) {
      f16x8 af = *(const f16x8*)(xp_cur + (arow + tap) * XSTR + q * 8);
      acc0 = __builtin_amdgcn_mfma_f32_16x16x32_f16(af, bfrag[tap][0], acc0, 0, 0, 0);
      acc1 = __builtin_amdgcn_mfma_f32_16x16x32_f16(af, bfrag[tap][1], acc1, 0, 0, 0);
    }
    float* orow = outb + (size_t)h * NW * NC;
    #pragma unroll
    for (int r = 0; r < 4; ++r) {
      float y0 = acc0[r] + bias0; y0 = y0 > 0.f ? y0 : 0.f;
      float y1 = acc1[r] + bias1; y1 = y1 > 0.f ? y1 : 0.f;
      int wo = wo0 + r;
      orow[wo * NC + n16]      = y0;
      orow[wo * NC + 16 + n16] = y1;
      if (h < NH - 1) {
        f16x2 v;
        v[0] = (f16)(pf[2 * r]     + y0);
        v[1] = (f16)(pf[2 * r + 1] + y1);
        *(f16x2*)(&xp_nxt[(wo + 2) * XSTR + 2 * n16]) = v;
      }
    }
    if (h + 3 < NH) load_in_row(h + 3, pf);
    lds_barrier();
  };

  const f16* xA = &xpad[0][0];
  f16* xB = &xpad[1][0];
  for (int h = 0; h < NH; h += 2) {
    body(h,     pf0, xA, xB);
    body(h + 1, pf1, xB, (f16*)xA);
  }
}

extern "C" void kernel_launch(void* const* d_in, const int* in_sizes, int n_in,
                              void* d_out, int out_size, void* d_ws, size_t ws_size,
                              hipStream_t stream) {
  const float* in   = (const float*)d_in[0];
  const float* wt   = (const float*)d_in[1];
  const float* bias = (const float*)d_in[2];
  float* out = (float*)d_out;

  const size_t need = (size_t)(MAIL_BASE + 256 * 2 * MAIL_WORDS) * 4;  // 528 KB
  if (d_ws != nullptr && ws_size >= need) {
    hipLaunchKernelGGL(reset_flags, dim3(16), dim3(256), 0, stream, (uint32_t*)d_ws);
    hipLaunchKernelGGL(mvcnn_down_mb, dim3(NB * GC), dim3(192), 0, stream,
                       in, wt, bias, out, (uint32_t*)d_ws);
  } else {
    hipLaunchKernelGGL(mvcnn_down, dim3(NB), dim3(1024), 0, stream,
                       in, wt, bias, out);
  }
}